// Round 3
// baseline (161.181 us; speedup 1.0000x reference)
//
#include <hip/hip_runtime.h>

#define Bn 16
#define Cn 256
#define HWn 9216
#define Pn 64
#define HEADSn 4
#define Gn 2304
#define STILE 64                     // spatial positions per block (4 waves x 16)
#define NBLK (Bn * HWn / STILE)      // 2304

typedef float f32x4 __attribute__((ext_vector_type(4)));
typedef short short8 __attribute__((ext_vector_type(8)));

static __device__ __forceinline__ unsigned short f2bf(float f) {
    unsigned int b = __builtin_bit_cast(unsigned int, f);
    unsigned int r = b + 0x7FFFu + ((b >> 16) & 1u);   // RNE
    return (unsigned short)(r >> 16);
}

// ---------------- K0: fold BN params + zero hm (replaces memset dispatch) -------
__global__ __launch_bounds__(256)
void k0_prep(const float* __restrict__ b1, const float* __restrict__ gamma,
             const float* __restrict__ beta, const float* __restrict__ mean,
             const float* __restrict__ var, float* __restrict__ scbc,
             float* __restrict__ hm)
{
    const int gid = blockIdx.x * 256 + threadIdx.x;
    if (gid < Bn * HEADSn * Pn) hm[gid] = 0.f;
    if (gid < Pn) {
        float s = gamma[gid] * rsqrtf(var[gid] + 1e-5f);
        scbc[gid] = s;
        scbc[Pn + gid] = (b1[gid] - mean[gid]) * s + beta[gid];
    }
}

// ------- K1/K3 shared GEMM1 pass. MODE 0: hm atomics. MODE 1: ctx + out. -------
template <int MODE>
__global__ __launch_bounds__(256, 2)
void gemm_pass(const float* __restrict__ x, const float* __restrict__ w1,
               const float* __restrict__ scbc, const float* __restrict__ wm,
               float* __restrict__ hm,
               const float* __restrict__ wmix, const float* __restrict__ bmix,
               float* __restrict__ out)
{
    __shared__ short w1l[Pn * Cn];    // bf16 w1, swizzled, 32 KB
    __shared__ short xl[Cn * STILE];  // bf16 x tile, swizzled, 32 KB
    __shared__ float ctxl[STILE];

    const int bid  = blockIdx.x;
    const int b    = bid / (HWn / STILE);
    const int tile = bid % (HWn / STILE);
    const int s0   = tile * STILE;
    const int head = s0 / Gn;                  // 64-tiles never straddle heads
    const int t    = threadIdx.x;
    const int lane = t & 63;
    const int wv   = t >> 6;
    const int g    = lane >> 4;                // 16-lane group
    const int m16  = lane & 15;

    // ---- issue ALL global loads first (max MLP): 16 float4 w1 + 16 float4 x ----
    f32x4 wk[8][2];
    {
        #pragma unroll
        for (int i = 0; i < 8; ++i) {
            const int cid = i * 256 + t;           // 2048 chunks of 8 floats
            const float* p = w1 + (cid << 3);      // w1 is dense [64][256]
            wk[i][0] = *reinterpret_cast<const f32x4*>(p);
            wk[i][1] = *reinterpret_cast<const f32x4*>(p + 4);
        }
    }
    const int c0 = t >> 3;                         // x rows: c0 + 32*i
    const int s8 = t & 7;                          // 8-float chunk within tile
    const float* xb = x + (size_t)b * Cn * HWn + s0 + s8 * 8;
    f32x4 xk[8][2];
    #pragma unroll
    for (int i = 0; i < 8; ++i) {
        const float* p = xb + (size_t)(c0 + 32 * i) * HWn;
        xk[i][0] = *reinterpret_cast<const f32x4*>(p);
        xk[i][1] = *reinterpret_cast<const f32x4*>(p + 4);
    }

    // ---- convert + write w1 to LDS: idx ^ ((row&7)<<3), 16B granules ----
    #pragma unroll
    for (int i = 0; i < 8; ++i) {
        const int cid = i * 256 + t;
        const int row = cid >> 5;
        const int kc  = (cid & 31) << 3;
        short8 v;
        #pragma unroll
        for (int j = 0; j < 4; ++j) { v[j] = (short)f2bf(wk[i][0][j]); v[4 + j] = (short)f2bf(wk[i][1][j]); }
        const int idx = (row * Cn + kc) ^ ((row & 7) << 3);
        *reinterpret_cast<short8*>(&w1l[idx]) = v;
    }
    // ---- convert + write x to LDS: idx = (c*64+s) ^ (((c&7)^((c>>3)&3))<<3) ----
    #pragma unroll
    for (int i = 0; i < 8; ++i) {
        const int c = c0 + 32 * i;
        short8 v;
        #pragma unroll
        for (int j = 0; j < 4; ++j) { v[j] = (short)f2bf(xk[i][0][j]); v[4 + j] = (short)f2bf(xk[i][1][j]); }
        const int f   = (c & 7) ^ ((c >> 3) & 3);
        const int idx = (c * STILE + s8 * 8) ^ (f << 3);
        *reinterpret_cast<short8*>(&xl[idx]) = v;
    }
    __syncthreads();

    // ---- GEMM1: D[p][s] = sum_c w1[p][c]*x[c][s], bf16 MFMA 16x16x32 ----
    f32x4 acc[4] = { {0,0,0,0}, {0,0,0,0}, {0,0,0,0}, {0,0,0,0} };
    const int sbase = wv * 16 + m16;               // this lane's column (spatial)
    #pragma unroll
    for (int ks = 0; ks < 8; ++ks) {
        short8 bf;
        #pragma unroll
        for (int j = 0; j < 8; ++j) {              // k = ks*32+g*8+j: (k&7)=j, ((k>>3)&3)=g
            const int k = ks * 32 + g * 8 + j;
            bf[j] = xl[(k * STILE + sbase) ^ ((j ^ g) << 3)];
        }
        #pragma unroll
        for (int rt = 0; rt < 4; ++rt) {
            const int row = rt * 16 + m16;
            const int idx = (row * Cn + ks * 32 + g * 8) ^ ((row & 7) << 3);
            const short8 af = *reinterpret_cast<const short8*>(&w1l[idx]);
            acc[rt] = __builtin_amdgcn_mfma_f32_16x16x32_bf16(af, bf, acc[rt], 0, 0, 0);
        }
    }

    // ---- BN + ReLU (C/D layout: col=lane&15, row=(lane>>4)*4+reg) ----
    float h[4][4];
    #pragma unroll
    for (int rt = 0; rt < 4; ++rt) {
        #pragma unroll
        for (int r = 0; r < 4; ++r) {
            const int p = rt * 16 + g * 4 + r;
            const float hv = acc[rt][r] * scbc[p] + scbc[Pn + p];
            h[rt][r] = hv > 0.f ? hv : 0.f;
        }
    }

    const int bh = b * HEADSn + head;
    if (MODE == 0) {
        // hm[p] += sum_s h[p][s]*wm[s] over this wave's 16 columns
        const float wmv = wm[s0 + sbase];
        #pragma unroll
        for (int rt = 0; rt < 4; ++rt) {
            #pragma unroll
            for (int r = 0; r < 4; ++r) {
                float v = h[rt][r] * wmv;
                v += __shfl_xor(v, 1); v += __shfl_xor(v, 2);
                v += __shfl_xor(v, 4); v += __shfl_xor(v, 8);
                if (m16 == 0)
                    atomicAdd(&hm[bh * Pn + rt * 16 + g * 4 + r], v);
            }
        }
    } else {
        // ctx[s] = sum_p wmix[p]*h[p][s] + bmix ; out = x + ctx (x kept in regs)
        const float* wmx = wmix + bh * Pn;
        float cp = 0.f;
        #pragma unroll
        for (int rt = 0; rt < 4; ++rt) {
            #pragma unroll
            for (int r = 0; r < 4; ++r)
                cp = fmaf(wmx[rt * 16 + g * 4 + r], h[rt][r], cp);
        }
        cp += __shfl_xor(cp, 16);
        cp += __shfl_xor(cp, 32);
        if (lane < 16) ctxl[sbase] = cp + bmix[bh];
        __syncthreads();

        const f32x4 cv0 = *reinterpret_cast<const f32x4*>(&ctxl[s8 * 8]);
        const f32x4 cv1 = *reinterpret_cast<const f32x4*>(&ctxl[s8 * 8 + 4]);
        float* ob = out + (size_t)b * Cn * HWn + s0 + s8 * 8;
        #pragma unroll
        for (int i = 0; i < 8; ++i) {
            float* p = ob + (size_t)(c0 + 32 * i) * HWn;
            f32x4 o0 = xk[i][0] + cv0;
            f32x4 o1 = xk[i][1] + cv1;
            *reinterpret_cast<f32x4*>(p)     = o0;
            *reinterpret_cast<f32x4*>(p + 4) = o1;
        }
    }
}

// ---------------- K2: logits -> softmax -> wmix/bmix (64 tiny blocks) ----------
__global__ __launch_bounds__(256)
void k2_mask(const float* __restrict__ hm, const float* __restrict__ w2,
             const float* __restrict__ b2, const float* __restrict__ wm,
             float* __restrict__ wmix, float* __restrict__ bmix)
{
    __shared__ float hms[Pn];
    __shared__ float masks[Cn];
    __shared__ float red[4];
    __shared__ float part[4][Pn];

    const int bh = blockIdx.x;
    const int head = bh & (HEADSn - 1);
    const int t = threadIdx.x;
    const int l = t & 63;
    const int wv = t >> 6;

    if (t < Pn) hms[t] = hm[bh * Pn + t];

    // wmsum over this head's group
    float wsum = 0.f;
    for (int i = t; i < Gn; i += 256) wsum += wm[head * Gn + i];
    #pragma unroll
    for (int d = 1; d < 64; d <<= 1) wsum += __shfl_xor(wsum, d);
    if (l == 0) red[wv] = wsum;
    __syncthreads();
    wsum = red[0] + red[1] + red[2] + red[3];

    // logits[c] = sum_k w2[c,k]*hm[k] + b2[c]*wsum
    float lg = 0.f;
    #pragma unroll
    for (int k = 0; k < Pn; ++k) lg = fmaf(w2[t * Pn + k], hms[k], lg);
    lg = fmaf(b2[t], wsum, lg);

    // softmax over 256 channels
    float mx = lg;
    #pragma unroll
    for (int d = 1; d < 64; d <<= 1) mx = fmaxf(mx, __shfl_xor(mx, d));
    __syncthreads();
    if (l == 0) red[wv] = mx;
    __syncthreads();
    mx = fmaxf(fmaxf(red[0], red[1]), fmaxf(red[2], red[3]));
    const float ev = __expf(lg - mx);
    float sm = ev;
    #pragma unroll
    for (int d = 1; d < 64; d <<= 1) sm += __shfl_xor(sm, d);
    __syncthreads();
    if (l == 0) red[wv] = sm;
    __syncthreads();
    sm = red[0] + red[1] + red[2] + red[3];
    masks[t] = ev / sm;
    __syncthreads();

    // wmix[k] = sum_c mask[c]*w2[c,k]
    {
        const int k = t & (Pn - 1);
        const int q = t >> 6;
        float wp = 0.f;
        #pragma unroll
        for (int i = 0; i < 64; ++i) {
            const int c = q * 64 + i;
            wp = fmaf(masks[c], w2[c * Pn + k], wp);
        }
        part[q][k] = wp;
    }
    __syncthreads();
    if (t < Pn) wmix[bh * Pn + t] = part[0][t] + part[1][t] + part[2][t] + part[3][t];

    // bmix = sum_c mask[c]*b2[c]
    float bp = masks[t] * b2[t];
    #pragma unroll
    for (int d = 1; d < 64; d <<= 1) bp += __shfl_xor(bp, d);
    __syncthreads();
    if (l == 0) red[wv] = bp;
    __syncthreads();
    if (t == 0) bmix[bh] = red[0] + red[1] + red[2] + red[3];
}

extern "C" void kernel_launch(void* const* d_in, const int* in_sizes, int n_in,
                              void* d_out, int out_size, void* d_ws, size_t ws_size,
                              hipStream_t stream)
{
    (void)in_sizes; (void)n_in; (void)out_size; (void)ws_size;
    const float* x     = (const float*)d_in[0];
    const float* w1    = (const float*)d_in[1];
    const float* b1    = (const float*)d_in[2];
    const float* gamma = (const float*)d_in[3];
    const float* beta  = (const float*)d_in[4];
    const float* mean  = (const float*)d_in[5];
    const float* var   = (const float*)d_in[6];
    const float* w2    = (const float*)d_in[7];
    const float* b2    = (const float*)d_in[8];
    const float* wm    = (const float*)d_in[9];
    // d_in[10] = bm: constant over softmax axis -> dropped

    float* out  = (float*)d_out;
    float* wsf  = (float*)d_ws;
    float* hm   = wsf;                       // [64*64]
    float* wmix = wsf + Bn * HEADSn * Pn;    // [64*64]
    float* bmix = wsf + 2 * Bn * HEADSn * Pn;// [64]
    float* scbc = bmix + 64;                 // [128]

    k0_prep<<<dim3(16), dim3(256), 0, stream>>>(b1, gamma, beta, mean, var, scbc, hm);
    gemm_pass<0><<<dim3(NBLK), dim3(256), 0, stream>>>(x, w1, scbc, wm, hm, nullptr, nullptr, nullptr);
    k2_mask<<<dim3(Bn * HEADSn), dim3(256), 0, stream>>>(hm, w2, b2, wm, wmix, bmix);
    gemm_pass<1><<<dim3(NBLK), dim3(256), 0, stream>>>(x, w1, scbc, wm, nullptr, wmix, bmix, out);
}

// Round 4
// 122.673 us; speedup vs baseline: 1.3139x; 1.3139x over previous
//
#include <hip/hip_runtime.h>

#define Bn 16
#define Cn 256
#define HWn 9216
#define Pn 64
#define HEADSn 4
#define Gn 2304
#define STILE 64
#define TILES_PER_B (HWn / STILE)    // 144
#define NBLK (Bn * TILES_PER_B)      // 2304

typedef float f32x4 __attribute__((ext_vector_type(4)));
typedef short short8 __attribute__((ext_vector_type(8)));

static __device__ __forceinline__ unsigned short f2bf(float f) {
    unsigned int b = __builtin_bit_cast(unsigned int, f);
    unsigned int r = b + 0x7FFFu + ((b >> 16) & 1u);   // RNE
    return (unsigned short)(r >> 16);
}

static __device__ __forceinline__ void gload_lds16(const void* g, void* l) {
    __builtin_amdgcn_global_load_lds((const __attribute__((address_space(1))) void*)g,
                                     (__attribute__((address_space(3))) void*)l, 16, 0, 0);
}

// ---- K0: scbc fold + w1 -> bf16 PRE-SWIZZLED into ws (so gemm can global_load_lds it) ----
__global__ __launch_bounds__(256)
void k0_prep(const float* __restrict__ w1, const float* __restrict__ b1,
             const float* __restrict__ gamma, const float* __restrict__ beta,
             const float* __restrict__ mean, const float* __restrict__ var,
             float* __restrict__ scbc, short* __restrict__ w1s)
{
    const int gid = blockIdx.x * 256 + threadIdx.x;
    if (gid < 2048) {                       // 2048 granules of 8 floats
        const int row = gid >> 5;
        const int kc  = (gid & 31) << 3;
        const float* p = w1 + row * Cn + kc;
        short8 v;
        #pragma unroll
        for (int j = 0; j < 8; ++j) v[j] = (short)f2bf(p[j]);
        const int idx = (row * Cn + kc) ^ ((row & 7) << 3);
        *reinterpret_cast<short8*>(&w1s[idx]) = v;
    }
    if (gid < Pn) {
        float s = gamma[gid] * rsqrtf(var[gid] + 1e-5f);
        scbc[gid] = s;
        scbc[Pn + gid] = (b1[gid] - mean[gid]) * s + beta[gid];
    }
}

// ------- gemm pass. MODE 0: per-block hm partials (NO global atomics). MODE 1: ctx+out. ----
template <int MODE>
__global__ __launch_bounds__(256, 2)
void gemm_pass(const float* __restrict__ x, const short* __restrict__ w1s,
               const float* __restrict__ scbc, const float* __restrict__ wm,
               float* __restrict__ hmp,
               const float* __restrict__ wmix, const float* __restrict__ bmix,
               float* __restrict__ out)
{
    __shared__ short w1l[Pn * Cn];    // 32 KB, arrives pre-swizzled via global_load_lds
    __shared__ short xl[Cn * STILE];  // 32 KB, bf16 swizzled
    __shared__ float ctxl[STILE];
    __shared__ float hml[Pn];

    const int bid  = blockIdx.x;
    const int b    = bid / TILES_PER_B;
    const int tile = bid % TILES_PER_B;
    const int s0   = tile * STILE;
    const int head = s0 / Gn;
    const int t    = threadIdx.x;
    const int lane = t & 63;
    const int wv   = t >> 6;
    const int g    = lane >> 4;
    const int m16  = lane & 15;

    // ---- w1: async linear LDS copy (zero VGPR), 8 x 1KB chunks per wave ----
    #pragma unroll
    for (int i = 0; i < 8; ++i) {
        const int chunk = i * 4 + wv;                   // 0..31, wave-uniform
        gload_lds16(w1s + chunk * 512 + lane * 8, &w1l[chunk * 512]);
    }

    // ---- x: issue ALL 16 dwordx4 first (full register budget now available) ----
    const int c0 = t >> 3;
    const int s8 = t & 7;
    const float* xb = x + (size_t)b * Cn * HWn + s0 + s8 * 8;
    f32x4 xa[16];
    #pragma unroll
    for (int i = 0; i < 8; ++i) {
        const float* p = xb + (size_t)(c0 + 32 * i) * HWn;
        xa[2 * i]     = *reinterpret_cast<const f32x4*>(p);
        xa[2 * i + 1] = *reinterpret_cast<const f32x4*>(p + 4);
    }
    // convert + swizzled LDS write: idx = (c*64+s) ^ (((c&7)^((c>>3)&3))<<3)
    #pragma unroll
    for (int i = 0; i < 8; ++i) {
        const int c = c0 + 32 * i;
        short8 v;
        #pragma unroll
        for (int j = 0; j < 4; ++j) { v[j] = (short)f2bf(xa[2 * i][j]); v[4 + j] = (short)f2bf(xa[2 * i + 1][j]); }
        const int f   = (c & 7) ^ ((c >> 3) & 3);
        const int idx = (c * STILE + s8 * 8) ^ (f << 3);
        *reinterpret_cast<short8*>(&xl[idx]) = v;
    }
    if (MODE == 0 && t < Pn) hml[t] = 0.f;
    __syncthreads();

    // ---- GEMM1: D[p][s] = sum_c w1[p][c]*x[c][s], bf16 MFMA 16x16x32 ----
    f32x4 acc[4] = { {0,0,0,0}, {0,0,0,0}, {0,0,0,0}, {0,0,0,0} };
    const int sbase = wv * 16 + m16;
    #pragma unroll
    for (int ks = 0; ks < 8; ++ks) {
        short8 bf;
        #pragma unroll
        for (int j = 0; j < 8; ++j) {
            const int k = ks * 32 + g * 8 + j;
            bf[j] = xl[(k * STILE + sbase) ^ ((j ^ g) << 3)];
        }
        #pragma unroll
        for (int rt = 0; rt < 4; ++rt) {
            const int row = rt * 16 + m16;
            const int idx = (row * Cn + ks * 32 + g * 8) ^ ((row & 7) << 3);
            const short8 af = *reinterpret_cast<const short8*>(&w1l[idx]);
            acc[rt] = __builtin_amdgcn_mfma_f32_16x16x32_bf16(af, bf, acc[rt], 0, 0, 0);
        }
    }

    // MODE1: re-issue the (L2-hot) x loads early; they drain under the epilogue
    f32x4 xr[16];
    if (MODE == 1) {
        #pragma unroll
        for (int i = 0; i < 8; ++i) {
            const float* p = xb + (size_t)(c0 + 32 * i) * HWn;
            xr[2 * i]     = *reinterpret_cast<const f32x4*>(p);
            xr[2 * i + 1] = *reinterpret_cast<const f32x4*>(p + 4);
        }
    }

    // ---- BN + ReLU (C/D layout: col=lane&15, row=(lane>>4)*4+reg) ----
    float h[4][4];
    #pragma unroll
    for (int rt = 0; rt < 4; ++rt) {
        #pragma unroll
        for (int r = 0; r < 4; ++r) {
            const int p = rt * 16 + g * 4 + r;
            const float hv = acc[rt][r] * scbc[p] + scbc[Pn + p];
            h[rt][r] = hv > 0.f ? hv : 0.f;
        }
    }

    if (MODE == 0) {
        // hm[p] partial = sum_s h[p][s]*wm[s]; combine 4 waves in LDS, one store per block
        const float wmv = wm[s0 + sbase];
        #pragma unroll
        for (int rt = 0; rt < 4; ++rt) {
            #pragma unroll
            for (int r = 0; r < 4; ++r) {
                float v = h[rt][r] * wmv;
                v += __shfl_xor(v, 1); v += __shfl_xor(v, 2);
                v += __shfl_xor(v, 4); v += __shfl_xor(v, 8);
                if (m16 == 0) atomicAdd(&hml[rt * 16 + g * 4 + r], v);   // LDS atomic
            }
        }
        __syncthreads();
        if (t < Pn) hmp[bid * Pn + t] = hml[t];
    } else {
        const int bh = b * HEADSn + head;
        const float* wmx = wmix + bh * Pn;
        float cp = 0.f;
        #pragma unroll
        for (int rt = 0; rt < 4; ++rt) {
            #pragma unroll
            for (int r = 0; r < 4; ++r)
                cp = fmaf(wmx[rt * 16 + g * 4 + r], h[rt][r], cp);
        }
        cp += __shfl_xor(cp, 16);
        cp += __shfl_xor(cp, 32);
        if (lane < 16) ctxl[sbase] = cp + bmix[bh];
        __syncthreads();

        const f32x4 cv0 = *reinterpret_cast<const f32x4*>(&ctxl[s8 * 8]);
        const f32x4 cv1 = *reinterpret_cast<const f32x4*>(&ctxl[s8 * 8 + 4]);
        float* ob = out + (size_t)b * Cn * HWn + s0 + s8 * 8;
        #pragma unroll
        for (int i = 0; i < 8; ++i) {
            float* p = ob + (size_t)(c0 + 32 * i) * HWn;
            *reinterpret_cast<f32x4*>(p)     = xr[2 * i] + cv0;
            *reinterpret_cast<f32x4*>(p + 4) = xr[2 * i + 1] + cv1;
        }
    }
}

// ---------------- K2: reduce hm partials -> logits -> softmax -> wmix/bmix ----------
__global__ __launch_bounds__(256)
void k2_mask(const float* __restrict__ hmp, const float* __restrict__ w2,
             const float* __restrict__ b2, const float* __restrict__ wm,
             float* __restrict__ wmix, float* __restrict__ bmix)
{
    __shared__ float hms[Pn];
    __shared__ float masks[Cn];
    __shared__ float red[4];
    __shared__ float part[4][Pn];

    const int bh = blockIdx.x;
    const int head = bh & (HEADSn - 1);
    const int t = threadIdx.x;
    const int l = t & 63;
    const int wv = t >> 6;

    // reduce 36 per-block partials for this (b,head)
    {
        const int p = t & 63, q = t >> 6;
        const float* base = hmp + ((size_t)(bh >> 2) * TILES_PER_B + (bh & 3) * 36) * Pn;
        float sp = 0.f;
        #pragma unroll
        for (int j = 0; j < 9; ++j) sp += base[(q + 4 * j) * Pn + p];
        part[q][p] = sp;
    }
    __syncthreads();
    if (t < Pn) hms[t] = part[0][t] + part[1][t] + part[2][t] + part[3][t];
    __syncthreads();

    // wmsum over this head's group
    float wsum = 0.f;
    for (int i = t; i < Gn; i += 256) wsum += wm[head * Gn + i];
    #pragma unroll
    for (int d = 1; d < 64; d <<= 1) wsum += __shfl_xor(wsum, d);
    if (l == 0) red[wv] = wsum;
    __syncthreads();
    wsum = red[0] + red[1] + red[2] + red[3];

    // logits[c] = sum_k w2[c,k]*hm[k] + b2[c]*wsum
    float lg = 0.f;
    #pragma unroll
    for (int k = 0; k < Pn; ++k) lg = fmaf(w2[t * Pn + k], hms[k], lg);
    lg = fmaf(b2[t], wsum, lg);

    // softmax over 256 channels
    float mx = lg;
    #pragma unroll
    for (int d = 1; d < 64; d <<= 1) mx = fmaxf(mx, __shfl_xor(mx, d));
    __syncthreads();
    if (l == 0) red[wv] = mx;
    __syncthreads();
    mx = fmaxf(fmaxf(red[0], red[1]), fmaxf(red[2], red[3]));
    const float ev = __expf(lg - mx);
    float sm = ev;
    #pragma unroll
    for (int d = 1; d < 64; d <<= 1) sm += __shfl_xor(sm, d);
    __syncthreads();
    if (l == 0) red[wv] = sm;
    __syncthreads();
    sm = red[0] + red[1] + red[2] + red[3];
    masks[t] = ev / sm;
    __syncthreads();

    // wmix[k] = sum_c mask[c]*w2[c,k]
    {
        const int k = t & (Pn - 1);
        const int q = t >> 6;
        float wp = 0.f;
        #pragma unroll
        for (int i = 0; i < 64; ++i) {
            const int c = q * 64 + i;
            wp = fmaf(masks[c], w2[c * Pn + k], wp);
        }
        part[q][k] = wp;
    }
    __syncthreads();
    if (t < Pn) wmix[bh * Pn + t] = part[0][t] + part[1][t] + part[2][t] + part[3][t];

    // bmix = sum_c mask[c]*b2[c]
    float bp = masks[t] * b2[t];
    #pragma unroll
    for (int d = 1; d < 64; d <<= 1) bp += __shfl_xor(bp, d);
    __syncthreads();
    if (l == 0) red[wv] = bp;
    __syncthreads();
    if (t == 0) bmix[bh] = red[0] + red[1] + red[2] + red[3];
}

extern "C" void kernel_launch(void* const* d_in, const int* in_sizes, int n_in,
                              void* d_out, int out_size, void* d_ws, size_t ws_size,
                              hipStream_t stream)
{
    (void)in_sizes; (void)n_in; (void)out_size; (void)ws_size;
    const float* x     = (const float*)d_in[0];
    const float* w1    = (const float*)d_in[1];
    const float* b1    = (const float*)d_in[2];
    const float* gamma = (const float*)d_in[3];
    const float* beta  = (const float*)d_in[4];
    const float* mean  = (const float*)d_in[5];
    const float* var   = (const float*)d_in[6];
    const float* w2    = (const float*)d_in[7];
    const float* b2    = (const float*)d_in[8];
    const float* wm    = (const float*)d_in[9];
    // d_in[10] = bm: constant over softmax axis -> dropped

    float* out  = (float*)d_out;
    float* wsf  = (float*)d_ws;
    float* hmp  = wsf;                            // [2304*64] f32 partials
    float* wmix = hmp + NBLK * Pn;                // [64*64]
    float* bmix = wmix + Bn * HEADSn * Pn;        // [64]
    float* scbc = bmix + 64;                      // [128]
    short* w1s  = (short*)(scbc + 128);           // [64*256] bf16 pre-swizzled

    k0_prep<<<dim3(8), dim3(256), 0, stream>>>(w1, b1, gamma, beta, mean, var, scbc, w1s);
    gemm_pass<0><<<dim3(NBLK), dim3(256), 0, stream>>>(x, w1s, scbc, wm, hmp, nullptr, nullptr, nullptr);
    k2_mask<<<dim3(Bn * HEADSn), dim3(256), 0, stream>>>(hmp, w2, b2, wm, wmix, bmix);
    gemm_pass<1><<<dim3(NBLK), dim3(256), 0, stream>>>(x, w1s, scbc, wm, nullptr, wmix, bmix, out);
}

// Round 6
// 107.948 us; speedup vs baseline: 1.4931x; 1.1364x over previous
//
#include <hip/hip_runtime.h>

#define Bn 16
#define Cn 256
#define HWn 9216
#define Pn 64
#define HEADSn 4
#define Gn 2304
#define STILE 64
#define TILES_PER_B (HWn / STILE)    // 144
#define NBLK (Bn * TILES_PER_B)      // 2304

typedef float f32x4 __attribute__((ext_vector_type(4)));
typedef short short4v __attribute__((ext_vector_type(4)));
typedef short short8 __attribute__((ext_vector_type(8)));

static __device__ __forceinline__ unsigned short f2bf(float f) {
    unsigned int b = __builtin_bit_cast(unsigned int, f);
    unsigned int r = b + 0x7FFFu + ((b >> 16) & 1u);   // RNE
    return (unsigned short)(r >> 16);
}
static __device__ __forceinline__ float bf2f(unsigned short u) {
    unsigned int b = ((unsigned int)u) << 16;
    return __builtin_bit_cast(float, b);
}
static __device__ __forceinline__ void gload_lds16(const void* g, void* l) {
    __builtin_amdgcn_global_load_lds((const __attribute__((address_space(1))) void*)g,
                                     (__attribute__((address_space(3))) void*)l, 16, 0, 0);
}

// ---- K0: scbc fold + w1 -> bf16 PRE-SWIZZLED into ws ----
__global__ __launch_bounds__(256)
void k0_prep(const float* __restrict__ w1, const float* __restrict__ b1,
             const float* __restrict__ gamma, const float* __restrict__ beta,
             const float* __restrict__ mean, const float* __restrict__ var,
             float* __restrict__ scbc, short* __restrict__ w1s)
{
    const int gid = blockIdx.x * 256 + threadIdx.x;
    if (gid < 2048) {                       // 2048 granules of 8 floats
        const int row = gid >> 5;
        const int kc  = (gid & 31) << 3;
        const float* p = w1 + row * Cn + kc;
        short8 v;
        #pragma unroll
        for (int j = 0; j < 8; ++j) v[j] = (short)f2bf(p[j]);
        const int idx = (row * Cn + kc) ^ ((row & 7) << 3);
        *reinterpret_cast<short8*>(&w1s[idx]) = v;
    }
    if (gid < Pn) {
        float s = gamma[gid] * rsqrtf(var[gid] + 1e-5f);
        scbc[gid] = s;
        scbc[Pn + gid] = (b1[gid] - mean[gid]) * s + beta[gid];
    }
}

// ---- K1: GEMM1 + BN/ReLU -> hm partials + h materialized as [b][s][p] bf16 ----
__global__ __launch_bounds__(256)
void k1_gemm(const float* __restrict__ x, const short* __restrict__ w1s,
             const float* __restrict__ scbc, const float* __restrict__ wm,
             float* __restrict__ hmp, short* __restrict__ hg)
{
    __shared__ short w1l[Pn * Cn];    // 32 KB, arrives pre-swizzled via global_load_lds
    __shared__ short xl[Cn * STILE];  // 32 KB; reused as ht[64][72] after MFMA
    __shared__ float hml[Pn];

    const int bid  = blockIdx.x;
    const int b    = bid / TILES_PER_B;
    const int tile = bid % TILES_PER_B;
    const int s0   = tile * STILE;
    const int t    = threadIdx.x;
    const int lane = t & 63;
    const int wv   = t >> 6;
    const int g    = lane >> 4;
    const int m16  = lane & 15;
    const int sbase = wv * 16 + m16;

    // ---- w1: async linear LDS copy (zero VGPR) ----
    #pragma unroll
    for (int i = 0; i < 8; ++i) {
        const int chunk = i * 4 + wv;                   // wave-uniform
        gload_lds16(w1s + chunk * 512 + lane * 8, &w1l[chunk * 512]);
    }

    // ---- x: DENSE loads: 16-lane group reads a full 256B row segment/instr ----
    const int c0 = t >> 4;                              // 0..15
    const int s4 = t & 15;                              // 0..15
    const float* xb = x + (size_t)b * Cn * HWn + s0 + s4 * 4;
    f32x4 xa[16];
    #pragma unroll
    for (int i = 0; i < 16; ++i)
        xa[i] = *reinterpret_cast<const f32x4*>(xb + (size_t)(c0 + 16 * i) * HWn);

    if (t < Pn) hml[t] = 0.f;

    // ---- convert + swizzled LDS write (4-elem/8B granules) ----
    // elem(c,s) -> (c*64+s) ^ (f(c)<<3), f(c) = (c&7)^((c>>3)&3)
    #pragma unroll
    for (int i = 0; i < 16; ++i) {
        const int c = c0 + 16 * i;
        short4v v;
        #pragma unroll
        for (int j = 0; j < 4; ++j) v[j] = (short)f2bf(xa[i][j]);
        const int f   = (c & 7) ^ ((c >> 3) & 3);
        const int idx = (c * STILE + s4 * 4) ^ (f << 3);
        *reinterpret_cast<short4v*>(&xl[idx]) = v;
    }
    __syncthreads();

    // ---- GEMM1: D[p][s] = sum_c w1[p][c]*x[c][s], bf16 MFMA 16x16x32 ----
    f32x4 acc[4] = { {0,0,0,0}, {0,0,0,0}, {0,0,0,0}, {0,0,0,0} };
    #pragma unroll
    for (int ks = 0; ks < 8; ++ks) {
        short8 bf;
        #pragma unroll
        for (int j = 0; j < 8; ++j) {                  // k=ks*32+g*8+j: f(k)=j^g
            const int k = ks * 32 + g * 8 + j;
            bf[j] = xl[(k * STILE + sbase) ^ ((j ^ g) << 3)];
        }
        #pragma unroll
        for (int rt = 0; rt < 4; ++rt) {
            const int row = rt * 16 + m16;
            const int idx = (row * Cn + ks * 32 + g * 8) ^ ((row & 7) << 3);
            const short8 af = *reinterpret_cast<const short8*>(&w1l[idx]);
            acc[rt] = __builtin_amdgcn_mfma_f32_16x16x32_bf16(af, bf, acc[rt], 0, 0, 0);
        }
    }

    // ---- BN + ReLU (C/D: col=lane&15 -> s, row=(lane>>4)*4+reg -> p_local) ----
    float h[4][4];
    #pragma unroll
    for (int rt = 0; rt < 4; ++rt) {
        #pragma unroll
        for (int r = 0; r < 4; ++r) {
            const int p = rt * 16 + g * 4 + r;
            const float hv = acc[rt][r] * scbc[p] + scbc[Pn + p];
            h[rt][r] = hv > 0.f ? hv : 0.f;
        }
    }

    // ---- hm partials: block-local LDS reduce, no global atomics ----
    const float wmv = wm[s0 + sbase];
    #pragma unroll
    for (int rt = 0; rt < 4; ++rt) {
        #pragma unroll
        for (int r = 0; r < 4; ++r) {
            float v = h[rt][r] * wmv;
            v += __shfl_xor(v, 1); v += __shfl_xor(v, 2);
            v += __shfl_xor(v, 4); v += __shfl_xor(v, 8);
            if (m16 == 0) atomicAdd(&hml[rt * 16 + g * 4 + r], v);   // LDS atomic
        }
    }
    __syncthreads();   // xl B-reads done everywhere + hml complete

    // ---- transpose h into ht[s][p] (reuse xl; pad row to 72 shorts) ----
    short* ht = xl;
    #pragma unroll
    for (int rt = 0; rt < 4; ++rt) {
        short4v hv;
        #pragma unroll
        for (int r = 0; r < 4; ++r) hv[r] = (short)f2bf(h[rt][r]);
        *reinterpret_cast<short4v*>(&ht[sbase * 72 + rt * 16 + g * 4]) = hv;
    }
    __syncthreads();

    // ---- coalesced h store: [64 s][64 p] -> hg[(b*HW + s0+s)*64 + p] ----
    {
        const int s = t >> 2, q = t & 3;
        const short8 a0 = *reinterpret_cast<const short8*>(&ht[s * 72 + q * 16]);
        const short8 a1 = *reinterpret_cast<const short8*>(&ht[s * 72 + q * 16 + 8]);
        short* dst = hg + ((size_t)b * HWn + s0 + s) * Pn + q * 16;
        *reinterpret_cast<short8*>(dst)     = a0;
        *reinterpret_cast<short8*>(dst + 8) = a1;
    }
    if (t < Pn) hmp[bid * Pn + t] = hml[t];
}

// ---- K2: reduce hm partials -> logits -> softmax -> wmix/bmix ----
__global__ __launch_bounds__(256)
void k2_mask(const float* __restrict__ hmp, const float* __restrict__ w2,
             const float* __restrict__ b2, const float* __restrict__ wm,
             float* __restrict__ wmix, float* __restrict__ bmix)
{
    __shared__ float hms[Pn];
    __shared__ float masks[Cn];
    __shared__ float red[4];
    __shared__ float part[4][Pn];

    const int bh = blockIdx.x;
    const int head = bh & (HEADSn - 1);
    const int t = threadIdx.x;
    const int l = t & 63;
    const int wv = t >> 6;

    // reduce 36 per-block partials for this (b,head)
    {
        const int p = t & 63, q = t >> 6;
        const float* base = hmp + ((size_t)(bh >> 2) * TILES_PER_B + (bh & 3) * 36) * Pn;
        float sp = 0.f;
        #pragma unroll
        for (int j = 0; j < 9; ++j) sp += base[(q + 4 * j) * Pn + p];
        part[q][p] = sp;
    }
    __syncthreads();
    if (t < Pn) hms[t] = part[0][t] + part[1][t] + part[2][t] + part[3][t];
    __syncthreads();

    // wmsum over this head's group
    float wsum = 0.f;
    for (int i = t; i < Gn; i += 256) wsum += wm[head * Gn + i];
    #pragma unroll
    for (int d = 1; d < 64; d <<= 1) wsum += __shfl_xor(wsum, d);
    if (l == 0) red[wv] = wsum;
    __syncthreads();
    wsum = red[0] + red[1] + red[2] + red[3];

    // logits[c] = sum_k w2[c,k]*hm[k] + b2[c]*wsum
    float lg = 0.f;
    #pragma unroll
    for (int k = 0; k < Pn; ++k) lg = fmaf(w2[t * Pn + k], hms[k], lg);
    lg = fmaf(b2[t], wsum, lg);

    // softmax over 256 channels
    float mx = lg;
    #pragma unroll
    for (int d = 1; d < 64; d <<= 1) mx = fmaxf(mx, __shfl_xor(mx, d));
    __syncthreads();
    if (l == 0) red[wv] = mx;
    __syncthreads();
    mx = fmaxf(fmaxf(red[0], red[1]), fmaxf(red[2], red[3]));
    const float ev = __expf(lg - mx);
    float sm = ev;
    #pragma unroll
    for (int d = 1; d < 64; d <<= 1) sm += __shfl_xor(sm, d);
    __syncthreads();
    if (l == 0) red[wv] = sm;
    __syncthreads();
    sm = red[0] + red[1] + red[2] + red[3];
    masks[t] = ev / sm;
    __syncthreads();

    // wmix[k] = sum_c mask[c]*w2[c,k]
    {
        const int k = t & (Pn - 1);
        const int q = t >> 6;
        float wp = 0.f;
        #pragma unroll
        for (int i = 0; i < 64; ++i) {
            const int c = q * 64 + i;
            wp = fmaf(masks[c], w2[c * Pn + k], wp);
        }
        part[q][k] = wp;
    }
    __syncthreads();
    if (t < Pn) wmix[bh * Pn + t] = part[0][t] + part[1][t] + part[2][t] + part[3][t];

    // bmix = sum_c mask[c]*b2[c]
    float bp = masks[t] * b2[t];
    #pragma unroll
    for (int d = 1; d < 64; d <<= 1) bp += __shfl_xor(bp, d);
    __syncthreads();
    if (l == 0) red[wv] = bp;
    __syncthreads();
    if (t == 0) bmix[bh] = red[0] + red[1] + red[2] + red[3];
}

// ---- K3: pure streaming: ctx[s] = wmix . h[s,:]; out = x + ctx ----
__global__ __launch_bounds__(256)
void k3_stream(const float* __restrict__ x, const short* __restrict__ hg,
               const float* __restrict__ wmix, const float* __restrict__ bmix,
               float* __restrict__ out)
{
    __shared__ float ctxl[STILE];

    const int bid  = blockIdx.x;
    const int b    = bid / TILES_PER_B;
    const int tile = bid % TILES_PER_B;
    const int s0   = tile * STILE;
    const int head = s0 / Gn;
    const int bh   = b * HEADSn + head;
    const int t    = threadIdx.x;

    if (t < STILE) {
        const short* hr = hg + ((size_t)b * HWn + s0 + t) * Pn;   // dense 128 B/lane
        const float* wmx = wmix + bh * Pn;
        float acc = 0.f;
        #pragma unroll
        for (int i = 0; i < 8; ++i) {
            const short8 v = *reinterpret_cast<const short8*>(hr + i * 8);
            const f32x4 w0 = *reinterpret_cast<const f32x4*>(wmx + i * 8);
            const f32x4 w1v = *reinterpret_cast<const f32x4*>(wmx + i * 8 + 4);
            #pragma unroll
            for (int j = 0; j < 4; ++j) {
                acc = fmaf(bf2f((unsigned short)v[j]), w0[j], acc);
                acc = fmaf(bf2f((unsigned short)v[4 + j]), w1v[j], acc);
            }
        }
        ctxl[t] = acc + bmix[bh];
    }
    __syncthreads();

    const int c0 = t >> 4;
    const int s4 = t & 15;
    const f32x4 cv = *reinterpret_cast<const f32x4*>(&ctxl[s4 * 4]);
    const float* xb = x + (size_t)b * Cn * HWn + s0 + s4 * 4;
    float* ob = out + (size_t)b * Cn * HWn + s0 + s4 * 4;
    #pragma unroll
    for (int i = 0; i < 16; ++i) {
        const size_t off = (size_t)(c0 + 16 * i) * HWn;
        *reinterpret_cast<f32x4*>(ob + off) =
            *reinterpret_cast<const f32x4*>(xb + off) + cv;
    }
}

extern "C" void kernel_launch(void* const* d_in, const int* in_sizes, int n_in,
                              void* d_out, int out_size, void* d_ws, size_t ws_size,
                              hipStream_t stream)
{
    (void)in_sizes; (void)n_in; (void)out_size; (void)ws_size;
    const float* x     = (const float*)d_in[0];
    const float* w1    = (const float*)d_in[1];
    const float* b1    = (const float*)d_in[2];
    const float* gamma = (const float*)d_in[3];
    const float* beta  = (const float*)d_in[4];
    const float* mean  = (const float*)d_in[5];
    const float* var   = (const float*)d_in[6];
    const float* w2    = (const float*)d_in[7];
    const float* b2    = (const float*)d_in[8];
    const float* wm    = (const float*)d_in[9];
    // d_in[10] = bm: constant over softmax axis -> dropped

    float* out  = (float*)d_out;
    float* wsf  = (float*)d_ws;
    float* hmp  = wsf;                            // [2304*64] f32
    float* wmix = hmp + NBLK * Pn;                // [64*64]
    float* bmix = wmix + Bn * HEADSn * Pn;        // [64]
    float* scbc = bmix + 64;                      // [128]
    short* w1s  = (short*)(scbc + 128);           // [64*256] bf16 pre-swizzled
    short* hg   = w1s + Pn * Cn;                  // [16*9216*64] bf16 — AFTER w1s (r5 bug: overlapped)

    k0_prep<<<dim3(8), dim3(256), 0, stream>>>(w1, b1, gamma, beta, mean, var, scbc, w1s);
    k1_gemm<<<dim3(NBLK), dim3(256), 0, stream>>>(x, w1s, scbc, wm, hmp, hg);
    k2_mask<<<dim3(Bn * HEADSn), dim3(256), 0, stream>>>(hmp, w2, b2, wm, wmix, bmix);
    k3_stream<<<dim3(NBLK), dim3(256), 0, stream>>>(x, hg, wmix, bmix, out);
}